// Round 1
// 407.299 us; speedup vs baseline: 1.0150x; 1.0150x over previous
//
#include <hip/hip_runtime.h>

#define NNODES 100000
#define NEDGES 3200000
#define NF 13
#define NFP 16       // padded f16 row stride for x
#define NG 512
#define BN_EPS 1e-5f
#define NTILES (NNODES / 16)   // 6250 exactly
#define CAP 72       // padded CSR slots per node (deg ~ Poisson(32); P(deg>72) ~ 1e-9)

#define BSH 9                          // bucket = 512 dst nodes
#define NBUCK ((NNODES + 511) / 512)   // 196
#define RCAP 18500                     // pairs per bucket (mean 16384, sigma ~128)
#define PTILE 4096
#define NPBLK ((NEDGES + PTILE - 1) / PTILE)  // 782

#define NCHUNK ((NNODES + 63) / 64)    // 1563 64-node chunks
#define NPTASK (3 * NCHUNK)            // wave-tasks for pooling

typedef __attribute__((ext_vector_type(8))) _Float16 f16x8;
typedef __attribute__((ext_vector_type(4))) _Float16 f16x4;
typedef __attribute__((ext_vector_type(4))) float f32x4;

__device__ __forceinline__ unsigned short f2h(float f) {
    union { _Float16 h; unsigned short u; } c;
    c.h = (_Float16)f;   // v_cvt_f16_f32, RNE
    return c.u;
}
__device__ __forceinline__ float h2f(unsigned short u) {
    union { _Float16 h; unsigned short u; } c;
    c.u = u;
    return (float)c.h;   // v_cvt_f32_f16
}

// packed-f16 cross-lane xor-shuffles (shuffle the dwords, add packed)
__device__ __forceinline__ f16x8 shfl_xor8(f16x8 v, int m) {
    union { f16x8 h; int i[4]; } a, b;
    a.h = v;
#pragma unroll
    for (int k = 0; k < 4; ++k) b.i[k] = __shfl_xor(a.i[k], m, 64);
    return b.h;
}
__device__ __forceinline__ f16x4 shfl_xor4(f16x4 v, int m) {
    union { f16x4 h; int i[2]; } a, b;
    a.h = v;
#pragma unroll
    for (int k = 0; k < 2; ++k) b.i[k] = __shfl_xor(a.i[k], m, 64);
    return b.h;
}

// ---------------- phase A: partition edges into 196 buckets of 512 dst nodes ----------
__launch_bounds__(256)
__global__ void partition_kernel(const int* __restrict__ src, const int* __restrict__ dst,
                                 int* __restrict__ gcount, int* __restrict__ pairbuf) {
    __shared__ int lhist[NBUCK];
    __shared__ int lbase[NBUCK];
    __shared__ int lpos[NBUCK];
    int t = threadIdx.x;
    int base = blockIdx.x * PTILE;
    int cnt = NEDGES - base; if (cnt > PTILE) cnt = PTILE;

    int v[PTILE / 256], b[PTILE / 256];
#pragma unroll
    for (int j = 0; j < PTILE / 256; ++j) {
        int i = t + j * 256;
        if (i < cnt) {
            int d = __builtin_nontemporal_load(dst + base + i);
            int s = __builtin_nontemporal_load(src + base + i);
            b[j] = d >> BSH;
            v[j] = ((d & 511) << 17) | s;
        } else b[j] = -1;
    }
    if (t < NBUCK) lhist[t] = 0;
    __syncthreads();
#pragma unroll
    for (int j = 0; j < PTILE / 256; ++j)
        if (b[j] >= 0) atomicAdd(&lhist[b[j]], 1);
    __syncthreads();
    if (t < NBUCK) {
        lbase[t] = atomicAdd(&gcount[t], lhist[t]);
        lpos[t] = 0;
    }
    __syncthreads();
#pragma unroll
    for (int j = 0; j < PTILE / 256; ++j) {
        if (b[j] >= 0) {
            int p = atomicAdd(&lpos[b[j]], 1);
            pairbuf[(size_t)b[j] * RCAP + lbase[b[j]] + p] = v[j];
        }
    }
}

// ---------------- phase B: per-bucket scatter with LDS cursors ----------------
__launch_bounds__(512)
__global__ void bucket_scatter_kernel(const int* __restrict__ pairbuf,
                                      const int* __restrict__ gcount,
                                      int* __restrict__ cursor, int* __restrict__ csr) {
    __shared__ int lcnt[512];
    int bk = blockIdx.x;
    int lo = bk << BSH;
    int cnt = gcount[bk];
    if (threadIdx.x < 512) lcnt[threadIdx.x] = 0;
    __syncthreads();
    const int* pb = pairbuf + (size_t)bk * RCAP;
    for (int i = threadIdx.x; i < cnt; i += 512) {
        int p = pb[i];
        int s = p & 0x1FFFF;
        int dl = p >> 17;
        int pos = atomicAdd(&lcnt[dl], 1);
        csr[(size_t)(lo + dl) * CAP + pos] = s;
    }
    __syncthreads();
    int n = lo + threadIdx.x;
    if (threadIdx.x < 512 && n < NNODES) cursor[n] = n * CAP + lcnt[threadIdx.x];
}

// ---------------- convert x (fp32, stride 13) -> xh (f16, stride 16, zero-padded) -----
__global__ void cvt_x_kernel(const float* __restrict__ x, unsigned short* __restrict__ xh) {
    const int total = NNODES * NFP;
    int idx = blockIdx.x * blockDim.x + threadIdx.x;
    int stride = gridDim.x * blockDim.x;
    for (int i = idx; i < total; i += stride) {
        int n = i >> 4;
        int f = i & 15;
        xh[i] = (f < NF) ? f2h(x[n * NF + f]) : (unsigned short)0;
    }
}

// ---------------- build MFMA B-fragments for all layer weights (f16) ----------------
__global__ void build_frags_kernel(const float* __restrict__ w10, const float* __restrict__ w20,
                                   const float* __restrict__ w11, const float* __restrict__ w21,
                                   const float* __restrict__ w12, const float* __restrict__ w22,
                                   unsigned short* __restrict__ wfrag) {
    int tid = blockIdx.x * blockDim.x + threadIdx.x;  // 3072 total
    if (tid >= 3072) return;
    int layer = tid >> 10;
    int rem = tid & 1023;
    int mat = rem >> 9;
    int tile = (rem >> 7) & 3;
    int chunk = (rem >> 6) & 1;
    int lane = rem & 63;
    int quad = lane >> 4, n = lane & 15;
    const float* W = (layer == 0) ? (mat ? w20 : w10)
                   : (layer == 1) ? (mat ? w21 : w11)
                                  : (mat ? w22 : w12);
    int K = (layer == 0 && mat == 0) ? NF : 64;
    unsigned short* o = wfrag + ((size_t)tid) * 8;
#pragma unroll
    for (int j = 0; j < 8; ++j) {
        int k = chunk * 32 + quad * 8 + j;
        float val = (k < K) ? W[k * 64 + tile * 16 + n] : 0.f;
        o[j] = f2h(val);
    }
}

// ---------------- packed-f16 aggregation, 16 edges/gather (layer 1: 32 B rows) --------
// Inner loop is acc(f16x4) += row(f16x4): 2 v_pk_add_f16 per 8 B, no converts.
template <int FSTR, int RL, int UNROLL, int PADZ>
__launch_bounds__(256, 8)
__global__ void agg_vec_kernel(const unsigned short* __restrict__ xin,
                               const int* __restrict__ cursor,
                               const int* __restrict__ csr,
                               unsigned short* __restrict__ y) {
    const int EPG = 64 / RL;
    int lane = threadIdx.x & 63;
    int g = lane / RL;
    int r = lane % RL;
    int wave = (blockIdx.x * blockDim.x + threadIdx.x) >> 6;
    int nw = (gridDim.x * blockDim.x) >> 6;

    for (int n = wave; n < NNODES; n += nw) {
        int beg = n * CAP;
        int end = cursor[n];
        f16x4 acc = {0, 0, 0, 0};
        if (g == 0)  // self row, added once
            acc = *(const f16x4*)&xin[n * FSTR + r * 4];
        int j = beg;
        const int STEP = UNROLL * EPG;
        for (; j + STEP <= end; j += STEP) {
#pragma unroll
            for (int t = 0; t < UNROLL; ++t) {
                int i0 = csr[j + t * EPG + g];       // guaranteed < end
                acc += *(const f16x4*)&xin[i0 * FSTR + r * 4];
            }
        }
        for (; j < end; j += EPG) {
            int e = j + g;
            if (e < end) {
                int i0 = csr[e];
                acc += *(const f16x4*)&xin[i0 * FSTR + r * 4];
            }
        }
#pragma unroll
        for (int m = RL; m < 64; m <<= 1) acc += shfl_xor4(acc, m);
        if (g == 0) {
            *(f16x4*)&y[n * 64 + r * 4] = acc;
        } else if (PADZ && g == 1) {
            f16x4 z = {0, 0, 0, 0};
            *(f16x4*)&y[n * 64 + 16 + r * 4] = z;
        }
    }
}

// ---------------- packed-f16 aggregation, 8 edges/gather (64-feature layers) ----------
// acc(f16x8) += row(f16x8): 4 v_pk_add_f16 per 16 B load (was 16 VALU ops as bf16).
__launch_bounds__(256, 8)
__global__ void agg_vec8_kernel(const unsigned short* __restrict__ xin,
                                const int* __restrict__ cursor,
                                const int* __restrict__ csr,
                                unsigned short* __restrict__ y) {
    int lane = threadIdx.x & 63;
    int g = lane >> 3;       // edge slot within gather [0,8)
    int r = lane & 7;        // row chunk: features r*8 .. r*8+7
    int wave = (blockIdx.x * blockDim.x + threadIdx.x) >> 6;
    int nw = (gridDim.x * blockDim.x) >> 6;

    for (int n = wave; n < NNODES; n += nw) {
        int beg = n * CAP;
        int end = cursor[n];
        f16x8 acc = {0, 0, 0, 0, 0, 0, 0, 0};
        if (g == 0)  // self row, added once
            acc = *(const f16x8*)&xin[(size_t)n * 64 + r * 8];
        int j = beg;
        for (; j + 16 <= end; j += 16) {   // two 8-edge gathers in flight
#pragma unroll
            for (int t = 0; t < 2; ++t) {
                int i0 = csr[j + t * 8 + g];
                acc += *(const f16x8*)&xin[(size_t)i0 * 64 + r * 8];
            }
        }
        for (; j < end; j += 8) {
            int e = j + g;
            if (e < end) {
                int i0 = csr[e];
                acc += *(const f16x8*)&xin[(size_t)i0 * 64 + r * 8];
            }
        }
        // reduce across the 8 edge-groups (masks 8,16,32), packed
#pragma unroll
        for (int m = 8; m < 64; m <<= 1) acc += shfl_xor8(acc, m);
        if (g == 0) *(f16x8*)&y[(size_t)n * 64 + r * 8] = acc;
    }
}

// ---------------- MFMA MLP: 16-node tile per wave (f16 MFMA, same layout as bf16) -----
template <int KC1>
__launch_bounds__(256)
__global__ void mlp_mfma_kernel(const unsigned short* __restrict__ yh,
                                const unsigned short* __restrict__ wfrag,
                                const float* __restrict__ b1, const float* __restrict__ g,
                                const float* __restrict__ be, const float* __restrict__ m,
                                const float* __restrict__ v,  const float* __restrict__ b2,
                                unsigned short* __restrict__ hout) {
    __shared__ __align__(16) unsigned short zs[4][16 * 72];  // per-wave slice, padded stride
    int lane = threadIdx.x & 63;
    int wid = threadIdx.x >> 6;
    int quad = lane >> 4;
    int n16 = lane & 15;

    const f16x8* wf = (const f16x8*)wfrag;
    f16x8 w1f[4][2], w2f[4][2];
#pragma unroll
    for (int t = 0; t < 4; ++t) {
#pragma unroll
        for (int c = 0; c < 2; ++c) {
            w1f[t][c] = wf[((0 * 4 + t) * 2 + c) * 64 + lane];
            w2f[t][c] = wf[((1 * 4 + t) * 2 + c) * 64 + lane];
        }
    }
    float scaleF[4], shiftF[4], b2F[4];
#pragma unroll
    for (int t = 0; t < 4; ++t) {
        int f = t * 16 + n16;
        float sc = g[f] * rsqrtf(v[f] + BN_EPS);
        scaleF[t] = sc;
        shiftF[t] = (b1[f] - m[f]) * sc + be[f];
        b2F[t] = b2[f];
    }

    unsigned short* zrow = &zs[wid][0];
    int ntiles = gridDim.x * 4;
    for (int tile = blockIdx.x * 4 + wid; tile < NTILES; tile += ntiles) {
        int nodebase = tile * 16;
        const unsigned short* yrow = yh + (size_t)(nodebase + n16) * 64 + quad * 8;
        f16x8 a0 = *(const f16x8*)yrow;
        f16x8 a1 = (KC1 == 2) ? *(const f16x8*)(yrow + 32) : a0;

        f32x4 acc[4];
#pragma unroll
        for (int t = 0; t < 4; ++t) {
            f32x4 z4 = {0.f, 0.f, 0.f, 0.f};
            z4 = __builtin_amdgcn_mfma_f32_16x16x32_f16(a0, w1f[t][0], z4, 0, 0, 0);
            if (KC1 == 2)
                z4 = __builtin_amdgcn_mfma_f32_16x16x32_f16(a1, w1f[t][1], z4, 0, 0, 0);
            acc[t] = z4;
        }
#pragma unroll
        for (int t = 0; t < 4; ++t) {
#pragma unroll
            for (int r = 0; r < 4; ++r) {
                float z = fmaxf(fmaf(acc[t][r], scaleF[t], shiftF[t]), 0.f);
                zrow[(quad * 4 + r) * 72 + t * 16 + n16] = f2h(z);
            }
        }
        __threadfence_block();
        f16x8 az0 = *(const f16x8*)&zrow[n16 * 72 + quad * 8];
        f16x8 az1 = *(const f16x8*)&zrow[n16 * 72 + 32 + quad * 8];

        f32x4 acc2[4];
#pragma unroll
        for (int t = 0; t < 4; ++t) {
            f32x4 z4 = {0.f, 0.f, 0.f, 0.f};
            z4 = __builtin_amdgcn_mfma_f32_16x16x32_f16(az0, w2f[t][0], z4, 0, 0, 0);
            z4 = __builtin_amdgcn_mfma_f32_16x16x32_f16(az1, w2f[t][1], z4, 0, 0, 0);
            acc2[t] = z4;
        }
#pragma unroll
        for (int t = 0; t < 4; ++t) {
#pragma unroll
            for (int r = 0; r < 4; ++r) {
                float h = fmaxf(acc2[t][r] + b2F[t], 0.f);
                hout[(size_t)(nodebase + quad * 4 + r) * 64 + t * 16 + n16] = f2h(h);
            }
        }
        __threadfence_block();
    }
}

// ---------------- pooling: one wave per (layer, 64-node chunk) ----------------
__launch_bounds__(256)
__global__ void pool_kernel(const unsigned short* __restrict__ h1,
                            const unsigned short* __restrict__ h2,
                            const unsigned short* __restrict__ h3,
                            const int* __restrict__ batch,
                            float* __restrict__ pool) {
    int task = blockIdx.x * 4 + (threadIdx.x >> 6);
    if (task >= NPTASK) return;
    int lane = threadIdx.x & 63;
    int layer = task / NCHUNK;
    int c = task - layer * NCHUNK;
    int n0 = c * 64;
    int n1 = n0 + 64; if (n1 > NNODES) n1 = NNODES;
    const unsigned short* hb = (layer == 0) ? h1 : (layer == 1) ? h2 : h3;
    float acc = 0.f;
    int curg = batch[n0];
    for (int n = n0; n < n1; ++n) {
        int gid = batch[n];
        if (gid != curg) {
            atomicAdd(&pool[(size_t)curg * 192 + layer * 64 + lane], acc);
            acc = 0.f;
            curg = gid;
        }
        acc += h2f(hb[(size_t)n * 64 + lane]);
    }
    atomicAdd(&pool[(size_t)curg * 192 + layer * 64 + lane], acc);
}

// ---------------- FC head on pooled features ----------------
__global__ void head_kernel(const float* __restrict__ pool,
                            const float* __restrict__ fc1W, const float* __restrict__ fc1b,
                            const float* __restrict__ fc2W, const float* __restrict__ fc2b,
                            float* __restrict__ out) {
    __shared__ float ps[192];
    __shared__ float hs[192];
    int gi = blockIdx.x;
    int t = threadIdx.x;  // 192
    ps[t] = pool[gi * 192 + t];
    __syncthreads();
    float acc = fc1b[t];
#pragma unroll 8
    for (int k = 0; k < 192; ++k) acc = fmaf(ps[k], fc1W[k * 192 + t], acc);
    hs[t] = fmaxf(acc, 0.f);
    __syncthreads();
    if (t == 0) {
        float l0 = fc2b[0], l1 = fc2b[1];
        for (int k = 0; k < 192; ++k) {
            float h = hs[k];
            l0 = fmaf(h, fc2W[k * 2 + 0], l0);
            l1 = fmaf(h, fc2W[k * 2 + 1], l1);
        }
        float mx = fmaxf(l0, l1);
        float lse = mx + logf(expf(l0 - mx) + expf(l1 - mx));
        out[gi * 2 + 0] = l0 - lse;
        out[gi * 2 + 1] = l1 - lse;
    }
}

extern "C" void kernel_launch(void* const* d_in, const int* in_sizes, int n_in,
                              void* d_out, int out_size, void* d_ws, size_t ws_size,
                              hipStream_t stream) {
    const float* x = (const float*)d_in[0];
    const int* src = (const int*)d_in[1];
    const int* dst = (const int*)d_in[2];
    const int* batch = (const int*)d_in[3];
    const float* c1[8];
    const float* c2[8];
    const float* c3[8];
    for (int i = 0; i < 8; ++i) {
        c1[i] = (const float*)d_in[4 + i];
        c2[i] = (const float*)d_in[12 + i];
        c3[i] = (const float*)d_in[20 + i];
    }
    const float* fc1W = (const float*)d_in[28];
    const float* fc1b = (const float*)d_in[29];
    const float* fc2W = (const float*)d_in[30];
    const float* fc2b = (const float*)d_in[31];
    float* out = (float*)d_out;

    // ---- workspace layout (all f16 activations) ----
    unsigned short* base = (unsigned short*)d_ws;
    const size_t NA = (size_t)NNODES * 64;
    unsigned short* yh  = base;                          // N*64
    unsigned short* xh  = yh + NA;                       // N*16
    unsigned short* h1  = xh + (size_t)NNODES * NFP;     // N*64
    unsigned short* h2  = h1 + NA;                       // N*64
    unsigned short* h3  = h2 + NA;                       // N*64
    unsigned short* wfrag = h3 + NA;                     // 3*8192 (16B-aligned)
    float* pool = (float*)(wfrag + 3 * 8192);            // G*192 fp32
    int* ibase = (int*)(pool + (size_t)NG * 192);
    int* cursor  = ibase;                             // N
    int* gcount  = ibase + NNODES;                    // NBUCK
    int* csr     = gcount + NBUCK;                    // N*CAP (+pad)
    int* pairbuf = csr + (size_t)NNODES * CAP + 256;  // NBUCK*RCAP

    hipMemsetAsync(gcount, 0, NBUCK * sizeof(int), stream);
    hipMemsetAsync(pool, 0, (size_t)NG * 192 * sizeof(float), stream);

    // ---- build padded CSR via 2-phase bucket partition + LDS-cursor scatter ----
    cvt_x_kernel<<<2048, 256, 0, stream>>>(x, xh);
    build_frags_kernel<<<12, 256, 0, stream>>>(c1[0], c1[6], c2[0], c2[6], c3[0], c3[6], wfrag);
    partition_kernel<<<NPBLK, 256, 0, stream>>>(src, dst, gcount, pairbuf);
    bucket_scatter_kernel<<<NBUCK, 512, 0, stream>>>(pairbuf, gcount, cursor, csr);

    const int AGG_BLOCKS = 25000;  // 4 waves/block -> one wave per node
    const int MLP_BLOCKS = 1024;

    // ---- layer 1 (fin=13, 32 B rows): 16 edges/gather; MFMA MLP with K=32 (1 chunk) ----
    agg_vec_kernel<NFP, 4, 2, 1><<<AGG_BLOCKS, 256, 0, stream>>>(xh, cursor, csr, yh);
    mlp_mfma_kernel<1><<<MLP_BLOCKS, 256, 0, stream>>>(
        yh, wfrag + 0 * 8192, c1[1], c1[2], c1[3], c1[4], c1[5], c1[7], h1);

    // ---- layer 2 (fin=64, 128 B rows): 8 edges/gather (16 B lanes); MFMA MLP K=64 ----
    agg_vec8_kernel<<<AGG_BLOCKS, 256, 0, stream>>>(h1, cursor, csr, yh);
    mlp_mfma_kernel<2><<<MLP_BLOCKS, 256, 0, stream>>>(
        yh, wfrag + 1 * 8192, c2[1], c2[2], c2[3], c2[4], c2[5], c2[7], h2);

    // ---- layer 3 (fin=64) ----
    agg_vec8_kernel<<<AGG_BLOCKS, 256, 0, stream>>>(h2, cursor, csr, yh);
    mlp_mfma_kernel<2><<<MLP_BLOCKS, 256, 0, stream>>>(
        yh, wfrag + 2 * 8192, c3[1], c3[2], c3[3], c3[4], c3[5], c3[7], h3);

    // ---- pooling (one wave per layer-chunk) + FC head ----
    pool_kernel<<<(NPTASK + 3) / 4, 256, 0, stream>>>(h1, h2, h3, batch, pool);
    head_kernel<<<NG, 192, 0, stream>>>(pool, fc1W, fc1b, fc2W, fc2b, out);
}

// Round 2
// 405.254 us; speedup vs baseline: 1.0201x; 1.0050x over previous
//
#include <hip/hip_runtime.h>

#define NNODES 100000
#define NEDGES 3200000
#define NF 13
#define NFP 16       // padded f16 row stride for x
#define NG 512
#define BN_EPS 1e-5f
#define NTILES (NNODES / 16)   // 6250 exactly
#define CAP 72       // padded CSR slots per node (deg ~ Poisson(32); P(deg>72) ~ 1e-9)

#define BSH 9                          // bucket = 512 dst nodes
#define NBUCK ((NNODES + 511) / 512)   // 196
#define RCAP 18500                     // pairs per bucket (mean 16384, sigma ~128)
#define PTILE 4096
#define NPBLK ((NEDGES + PTILE - 1) / PTILE)  // 782

#define NCHUNK ((NNODES + 63) / 64)    // 1563 64-node chunks
#define NPTASK (3 * NCHUNK)            // wave-tasks for pooling

typedef __attribute__((ext_vector_type(8))) _Float16 f16x8;
typedef __attribute__((ext_vector_type(4))) _Float16 f16x4;
typedef __attribute__((ext_vector_type(4))) float f32x4;

__device__ __forceinline__ unsigned short f2h(float f) {
    union { _Float16 h; unsigned short u; } c;
    c.h = (_Float16)f;   // v_cvt_f16_f32, RNE
    return c.u;
}
__device__ __forceinline__ float h2f(unsigned short u) {
    union { _Float16 h; unsigned short u; } c;
    c.u = u;
    return (float)c.h;   // v_cvt_f32_f16
}

// packed-f16 cross-lane xor-shuffles (shuffle the dwords, add packed)
__device__ __forceinline__ f16x8 shfl_xor8(f16x8 v, int m) {
    union { f16x8 h; int i[4]; } a, b;
    a.h = v;
#pragma unroll
    for (int k = 0; k < 4; ++k) b.i[k] = __shfl_xor(a.i[k], m, 64);
    return b.h;
}
__device__ __forceinline__ f16x4 shfl_xor4(f16x4 v, int m) {
    union { f16x4 h; int i[2]; } a, b;
    a.h = v;
#pragma unroll
    for (int k = 0; k < 2; ++k) b.i[k] = __shfl_xor(a.i[k], m, 64);
    return b.h;
}

// ---------------- phase A: partition edges into 196 buckets of 512 dst nodes ----------
__launch_bounds__(256)
__global__ void partition_kernel(const int* __restrict__ src, const int* __restrict__ dst,
                                 int* __restrict__ gcount, int* __restrict__ pairbuf) {
    __shared__ int lhist[NBUCK];
    __shared__ int lbase[NBUCK];
    __shared__ int lpos[NBUCK];
    int t = threadIdx.x;
    int base = blockIdx.x * PTILE;
    int cnt = NEDGES - base; if (cnt > PTILE) cnt = PTILE;

    int v[PTILE / 256], b[PTILE / 256];
#pragma unroll
    for (int j = 0; j < PTILE / 256; ++j) {
        int i = t + j * 256;
        if (i < cnt) {
            int d = __builtin_nontemporal_load(dst + base + i);
            int s = __builtin_nontemporal_load(src + base + i);
            b[j] = d >> BSH;
            v[j] = ((d & 511) << 17) | s;
        } else b[j] = -1;
    }
    if (t < NBUCK) lhist[t] = 0;
    __syncthreads();
#pragma unroll
    for (int j = 0; j < PTILE / 256; ++j)
        if (b[j] >= 0) atomicAdd(&lhist[b[j]], 1);
    __syncthreads();
    if (t < NBUCK) {
        lbase[t] = atomicAdd(&gcount[t], lhist[t]);
        lpos[t] = 0;
    }
    __syncthreads();
#pragma unroll
    for (int j = 0; j < PTILE / 256; ++j) {
        if (b[j] >= 0) {
            int p = atomicAdd(&lpos[b[j]], 1);
            pairbuf[(size_t)b[j] * RCAP + lbase[b[j]] + p] = v[j];
        }
    }
}

// ---------------- phase B: per-bucket scatter with LDS cursors ----------------
__launch_bounds__(512)
__global__ void bucket_scatter_kernel(const int* __restrict__ pairbuf,
                                      const int* __restrict__ gcount,
                                      int* __restrict__ cursor, int* __restrict__ csr) {
    __shared__ int lcnt[512];
    int bk = blockIdx.x;
    int lo = bk << BSH;
    int cnt = gcount[bk];
    if (threadIdx.x < 512) lcnt[threadIdx.x] = 0;
    __syncthreads();
    const int* pb = pairbuf + (size_t)bk * RCAP;
    for (int i = threadIdx.x; i < cnt; i += 512) {
        int p = pb[i];
        int s = p & 0x1FFFF;
        int dl = p >> 17;
        int pos = atomicAdd(&lcnt[dl], 1);
        csr[(size_t)(lo + dl) * CAP + pos] = s;
    }
    __syncthreads();
    int n = lo + threadIdx.x;
    if (threadIdx.x < 512 && n < NNODES) cursor[n] = n * CAP + lcnt[threadIdx.x];
}

// ---------------- convert x (fp32, stride 13) -> xh (f16, stride 16, zero-padded) -----
__global__ void cvt_x_kernel(const float* __restrict__ x, unsigned short* __restrict__ xh) {
    const int total = NNODES * NFP;
    int idx = blockIdx.x * blockDim.x + threadIdx.x;
    int stride = gridDim.x * blockDim.x;
    for (int i = idx; i < total; i += stride) {
        int n = i >> 4;
        int f = i & 15;
        xh[i] = (f < NF) ? f2h(x[n * NF + f]) : (unsigned short)0;
    }
}

// ---------------- build MFMA B-fragments for all layer weights (f16) ----------------
__global__ void build_frags_kernel(const float* __restrict__ w10, const float* __restrict__ w20,
                                   const float* __restrict__ w11, const float* __restrict__ w21,
                                   const float* __restrict__ w12, const float* __restrict__ w22,
                                   unsigned short* __restrict__ wfrag) {
    int tid = blockIdx.x * blockDim.x + threadIdx.x;  // 3072 total
    if (tid >= 3072) return;
    int layer = tid >> 10;
    int rem = tid & 1023;
    int mat = rem >> 9;
    int tile = (rem >> 7) & 3;
    int chunk = (rem >> 6) & 1;
    int lane = rem & 63;
    int quad = lane >> 4, n = lane & 15;
    const float* W = (layer == 0) ? (mat ? w20 : w10)
                   : (layer == 1) ? (mat ? w21 : w11)
                                  : (mat ? w22 : w12);
    int K = (layer == 0 && mat == 0) ? NF : 64;
    unsigned short* o = wfrag + ((size_t)tid) * 8;
#pragma unroll
    for (int j = 0; j < 8; ++j) {
        int k = chunk * 32 + quad * 8 + j;
        float val = (k < K) ? W[k * 64 + tile * 16 + n] : 0.f;
        o[j] = f2h(val);
    }
}

// ---------------- packed-f16 aggregation, layer 1 (32 B rows), 2 nodes per wave -------
// 16 edges/gather; joint loop keeps 2 independent gathers (one per node) in flight.
template <int FSTR, int RL, int PADZ>
__launch_bounds__(256, 8)
__global__ void agg_vec_kernel(const unsigned short* __restrict__ xin,
                               const int* __restrict__ cursor,
                               const int* __restrict__ csr,
                               unsigned short* __restrict__ y) {
    const int EPG = 64 / RL;     // 16 edges per gather
    int lane = threadIdx.x & 63;
    int g = lane / RL;
    int r = lane % RL;
    int wave = (blockIdx.x * blockDim.x + threadIdx.x) >> 6;
    int nw = (gridDim.x * blockDim.x) >> 6;

    for (int n0 = wave * 2; n0 < NNODES; n0 += nw * 2) {
        int nA = n0, nB = n0 + 1;
        int jA = nA * CAP, endA = cursor[nA];
        int jB = nB * CAP, endB = cursor[nB];
        f16x4 accA = {0, 0, 0, 0};
        f16x4 accB = {0, 0, 0, 0};
        if (g == 0) {  // self rows, added once
            accA = *(const f16x4*)&xin[nA * FSTR + r * 4];
            accB = *(const f16x4*)&xin[nB * FSTR + r * 4];
        }
        // joint main loop: one 16-edge gather per node per iter (2 in flight)
        while (jA + EPG <= endA && jB + EPG <= endB) {
            int iA = csr[jA + g];
            int iB = csr[jB + g];
            f16x4 vA = *(const f16x4*)&xin[iA * FSTR + r * 4];
            f16x4 vB = *(const f16x4*)&xin[iB * FSTR + r * 4];
            accA += vA; accB += vB;
            jA += EPG; jB += EPG;
        }
        // finish node A
        for (; jA + 2 * EPG <= endA; jA += 2 * EPG) {
            int i0 = csr[jA + g], i1 = csr[jA + EPG + g];
            f16x4 v0 = *(const f16x4*)&xin[i0 * FSTR + r * 4];
            f16x4 v1 = *(const f16x4*)&xin[i1 * FSTR + r * 4];
            accA += v0; accA += v1;
        }
        for (; jA < endA; jA += EPG) {
            int e = jA + g;
            if (e < endA) {
                int i0 = csr[e];
                accA += *(const f16x4*)&xin[i0 * FSTR + r * 4];
            }
        }
        // finish node B
        for (; jB + 2 * EPG <= endB; jB += 2 * EPG) {
            int i0 = csr[jB + g], i1 = csr[jB + EPG + g];
            f16x4 v0 = *(const f16x4*)&xin[i0 * FSTR + r * 4];
            f16x4 v1 = *(const f16x4*)&xin[i1 * FSTR + r * 4];
            accB += v0; accB += v1;
        }
        for (; jB < endB; jB += EPG) {
            int e = jB + g;
            if (e < endB) {
                int i0 = csr[e];
                accB += *(const f16x4*)&xin[i0 * FSTR + r * 4];
            }
        }
        // interleaved reductions (independent lgkm chains overlap)
#pragma unroll
        for (int m = RL; m < 64; m <<= 1) {
            accA += shfl_xor4(accA, m);
            accB += shfl_xor4(accB, m);
        }
        if (g == 0) {
            *(f16x4*)&y[nA * 64 + r * 4] = accA;
            *(f16x4*)&y[nB * 64 + r * 4] = accB;
        } else if (PADZ && g == 1) {
            f16x4 z = {0, 0, 0, 0};
            *(f16x4*)&y[nA * 64 + 16 + r * 4] = z;
            *(f16x4*)&y[nB * 64 + 16 + r * 4] = z;
        }
    }
}

// ---------------- packed-f16 aggregation, 64-feature layers, 2 nodes per wave ---------
// 8 edges/gather; joint loop keeps 4 independent 1KB gathers in flight per wave.
__launch_bounds__(256, 8)
__global__ void agg_vec8_kernel(const unsigned short* __restrict__ xin,
                                const int* __restrict__ cursor,
                                const int* __restrict__ csr,
                                unsigned short* __restrict__ y) {
    int lane = threadIdx.x & 63;
    int g = lane >> 3;       // edge slot within gather [0,8)
    int r = lane & 7;        // row chunk: features r*8 .. r*8+7
    int wave = (blockIdx.x * blockDim.x + threadIdx.x) >> 6;
    int nw = (gridDim.x * blockDim.x) >> 6;

    for (int n0 = wave * 2; n0 < NNODES; n0 += nw * 2) {
        int nA = n0, nB = n0 + 1;
        int jA = nA * CAP, endA = cursor[nA];
        int jB = nB * CAP, endB = cursor[nB];
        f16x8 accA = {0, 0, 0, 0, 0, 0, 0, 0};
        f16x8 accB = {0, 0, 0, 0, 0, 0, 0, 0};
        if (g == 0) {  // self rows, added once
            accA = *(const f16x8*)&xin[(size_t)nA * 64 + r * 8];
            accB = *(const f16x8*)&xin[(size_t)nB * 64 + r * 8];
        }
        // joint main loop: 2 gathers per node per iter -> 4 in flight
        while (jA + 16 <= endA && jB + 16 <= endB) {
            int iA0 = csr[jA + g];
            int iA1 = csr[jA + 8 + g];
            int iB0 = csr[jB + g];
            int iB1 = csr[jB + 8 + g];
            f16x8 vA0 = *(const f16x8*)&xin[(size_t)iA0 * 64 + r * 8];
            f16x8 vA1 = *(const f16x8*)&xin[(size_t)iA1 * 64 + r * 8];
            f16x8 vB0 = *(const f16x8*)&xin[(size_t)iB0 * 64 + r * 8];
            f16x8 vB1 = *(const f16x8*)&xin[(size_t)iB1 * 64 + r * 8];
            accA += vA0; accA += vA1;
            accB += vB0; accB += vB1;
            jA += 16; jB += 16;
        }
        // finish node A
        for (; jA + 16 <= endA; jA += 16) {
            int i0 = csr[jA + g], i1 = csr[jA + 8 + g];
            f16x8 v0 = *(const f16x8*)&xin[(size_t)i0 * 64 + r * 8];
            f16x8 v1 = *(const f16x8*)&xin[(size_t)i1 * 64 + r * 8];
            accA += v0; accA += v1;
        }
        for (; jA < endA; jA += 8) {
            int e = jA + g;
            if (e < endA) {
                int i0 = csr[e];
                accA += *(const f16x8*)&xin[(size_t)i0 * 64 + r * 8];
            }
        }
        // finish node B
        for (; jB + 16 <= endB; jB += 16) {
            int i0 = csr[jB + g], i1 = csr[jB + 8 + g];
            f16x8 v0 = *(const f16x8*)&xin[(size_t)i0 * 64 + r * 8];
            f16x8 v1 = *(const f16x8*)&xin[(size_t)i1 * 64 + r * 8];
            accB += v0; accB += v1;
        }
        for (; jB < endB; jB += 8) {
            int e = jB + g;
            if (e < endB) {
                int i0 = csr[e];
                accB += *(const f16x8*)&xin[(size_t)i0 * 64 + r * 8];
            }
        }
        // interleaved reductions across edge-groups (masks 8,16,32)
#pragma unroll
        for (int m = 8; m < 64; m <<= 1) {
            accA += shfl_xor8(accA, m);
            accB += shfl_xor8(accB, m);
        }
        if (g == 0) {
            *(f16x8*)&y[(size_t)nA * 64 + r * 8] = accA;
            *(f16x8*)&y[(size_t)nB * 64 + r * 8] = accB;
        }
    }
}

// ---------------- MFMA MLP: 16-node tile per wave (f16 MFMA) --------------------------
template <int KC1>
__launch_bounds__(256)
__global__ void mlp_mfma_kernel(const unsigned short* __restrict__ yh,
                                const unsigned short* __restrict__ wfrag,
                                const float* __restrict__ b1, const float* __restrict__ g,
                                const float* __restrict__ be, const float* __restrict__ m,
                                const float* __restrict__ v,  const float* __restrict__ b2,
                                unsigned short* __restrict__ hout) {
    __shared__ __align__(16) unsigned short zs[4][16 * 72];  // per-wave slice, padded stride
    int lane = threadIdx.x & 63;
    int wid = threadIdx.x >> 6;
    int quad = lane >> 4;
    int n16 = lane & 15;

    const f16x8* wf = (const f16x8*)wfrag;
    f16x8 w1f[4][2], w2f[4][2];
#pragma unroll
    for (int t = 0; t < 4; ++t) {
#pragma unroll
        for (int c = 0; c < 2; ++c) {
            w1f[t][c] = wf[((0 * 4 + t) * 2 + c) * 64 + lane];
            w2f[t][c] = wf[((1 * 4 + t) * 2 + c) * 64 + lane];
        }
    }
    float scaleF[4], shiftF[4], b2F[4];
#pragma unroll
    for (int t = 0; t < 4; ++t) {
        int f = t * 16 + n16;
        float sc = g[f] * rsqrtf(v[f] + BN_EPS);
        scaleF[t] = sc;
        shiftF[t] = (b1[f] - m[f]) * sc + be[f];
        b2F[t] = b2[f];
    }

    unsigned short* zrow = &zs[wid][0];
    int ntiles = gridDim.x * 4;
    for (int tile = blockIdx.x * 4 + wid; tile < NTILES; tile += ntiles) {
        int nodebase = tile * 16;
        const unsigned short* yrow = yh + (size_t)(nodebase + n16) * 64 + quad * 8;
        f16x8 a0 = *(const f16x8*)yrow;
        f16x8 a1 = (KC1 == 2) ? *(const f16x8*)(yrow + 32) : a0;

        f32x4 acc[4];
#pragma unroll
        for (int t = 0; t < 4; ++t) {
            f32x4 z4 = {0.f, 0.f, 0.f, 0.f};
            z4 = __builtin_amdgcn_mfma_f32_16x16x32_f16(a0, w1f[t][0], z4, 0, 0, 0);
            if (KC1 == 2)
                z4 = __builtin_amdgcn_mfma_f32_16x16x32_f16(a1, w1f[t][1], z4, 0, 0, 0);
            acc[t] = z4;
        }
#pragma unroll
        for (int t = 0; t < 4; ++t) {
#pragma unroll
            for (int r = 0; r < 4; ++r) {
                float z = fmaxf(fmaf(acc[t][r], scaleF[t], shiftF[t]), 0.f);
                zrow[(quad * 4 + r) * 72 + t * 16 + n16] = f2h(z);
            }
        }
        __threadfence_block();
        f16x8 az0 = *(const f16x8*)&zrow[n16 * 72 + quad * 8];
        f16x8 az1 = *(const f16x8*)&zrow[n16 * 72 + 32 + quad * 8];

        f32x4 acc2[4];
#pragma unroll
        for (int t = 0; t < 4; ++t) {
            f32x4 z4 = {0.f, 0.f, 0.f, 0.f};
            z4 = __builtin_amdgcn_mfma_f32_16x16x32_f16(az0, w2f[t][0], z4, 0, 0, 0);
            z4 = __builtin_amdgcn_mfma_f32_16x16x32_f16(az1, w2f[t][1], z4, 0, 0, 0);
            acc2[t] = z4;
        }
#pragma unroll
        for (int t = 0; t < 4; ++t) {
#pragma unroll
            for (int r = 0; r < 4; ++r) {
                float h = fmaxf(acc2[t][r] + b2F[t], 0.f);
                hout[(size_t)(nodebase + quad * 4 + r) * 64 + t * 16 + n16] = f2h(h);
            }
        }
        __threadfence_block();
    }
}

// ---------------- pooling: one wave per (layer, 64-node chunk) ----------------
__launch_bounds__(256)
__global__ void pool_kernel(const unsigned short* __restrict__ h1,
                            const unsigned short* __restrict__ h2,
                            const unsigned short* __restrict__ h3,
                            const int* __restrict__ batch,
                            float* __restrict__ pool) {
    int task = blockIdx.x * 4 + (threadIdx.x >> 6);
    if (task >= NPTASK) return;
    int lane = threadIdx.x & 63;
    int layer = task / NCHUNK;
    int c = task - layer * NCHUNK;
    int n0 = c * 64;
    int n1 = n0 + 64; if (n1 > NNODES) n1 = NNODES;
    const unsigned short* hb = (layer == 0) ? h1 : (layer == 1) ? h2 : h3;
    float acc = 0.f;
    int curg = batch[n0];
    for (int n = n0; n < n1; ++n) {
        int gid = batch[n];
        if (gid != curg) {
            atomicAdd(&pool[(size_t)curg * 192 + layer * 64 + lane], acc);
            acc = 0.f;
            curg = gid;
        }
        acc += h2f(hb[(size_t)n * 64 + lane]);
    }
    atomicAdd(&pool[(size_t)curg * 192 + layer * 64 + lane], acc);
}

// ---------------- FC head on pooled features ----------------
__global__ void head_kernel(const float* __restrict__ pool,
                            const float* __restrict__ fc1W, const float* __restrict__ fc1b,
                            const float* __restrict__ fc2W, const float* __restrict__ fc2b,
                            float* __restrict__ out) {
    __shared__ float ps[192];
    __shared__ float hs[192];
    int gi = blockIdx.x;
    int t = threadIdx.x;  // 192
    ps[t] = pool[gi * 192 + t];
    __syncthreads();
    float acc = fc1b[t];
#pragma unroll 8
    for (int k = 0; k < 192; ++k) acc = fmaf(ps[k], fc1W[k * 192 + t], acc);
    hs[t] = fmaxf(acc, 0.f);
    __syncthreads();
    if (t == 0) {
        float l0 = fc2b[0], l1 = fc2b[1];
        for (int k = 0; k < 192; ++k) {
            float h = hs[k];
            l0 = fmaf(h, fc2W[k * 2 + 0], l0);
            l1 = fmaf(h, fc2W[k * 2 + 1], l1);
        }
        float mx = fmaxf(l0, l1);
        float lse = mx + logf(expf(l0 - mx) + expf(l1 - mx));
        out[gi * 2 + 0] = l0 - lse;
        out[gi * 2 + 1] = l1 - lse;
    }
}

extern "C" void kernel_launch(void* const* d_in, const int* in_sizes, int n_in,
                              void* d_out, int out_size, void* d_ws, size_t ws_size,
                              hipStream_t stream) {
    const float* x = (const float*)d_in[0];
    const int* src = (const int*)d_in[1];
    const int* dst = (const int*)d_in[2];
    const int* batch = (const int*)d_in[3];
    const float* c1[8];
    const float* c2[8];
    const float* c3[8];
    for (int i = 0; i < 8; ++i) {
        c1[i] = (const float*)d_in[4 + i];
        c2[i] = (const float*)d_in[12 + i];
        c3[i] = (const float*)d_in[20 + i];
    }
    const float* fc1W = (const float*)d_in[28];
    const float* fc1b = (const float*)d_in[29];
    const float* fc2W = (const float*)d_in[30];
    const float* fc2b = (const float*)d_in[31];
    float* out = (float*)d_out;

    // ---- workspace layout (all f16 activations) ----
    unsigned short* base = (unsigned short*)d_ws;
    const size_t NA = (size_t)NNODES * 64;
    unsigned short* yh  = base;                          // N*64
    unsigned short* xh  = yh + NA;                       // N*16
    unsigned short* h1  = xh + (size_t)NNODES * NFP;     // N*64
    unsigned short* h2  = h1 + NA;                       // N*64
    unsigned short* h3  = h2 + NA;                       // N*64
    unsigned short* wfrag = h3 + NA;                     // 3*8192 (16B-aligned)
    float* pool = (float*)(wfrag + 3 * 8192);            // G*192 fp32
    int* ibase = (int*)(pool + (size_t)NG * 192);
    int* cursor  = ibase;                             // N
    int* gcount  = ibase + NNODES;                    // NBUCK
    int* csr     = gcount + NBUCK;                    // N*CAP (+pad)
    int* pairbuf = csr + (size_t)NNODES * CAP + 256;  // NBUCK*RCAP

    hipMemsetAsync(gcount, 0, NBUCK * sizeof(int), stream);
    hipMemsetAsync(pool, 0, (size_t)NG * 192 * sizeof(float), stream);

    // ---- build padded CSR via 2-phase bucket partition + LDS-cursor scatter ----
    cvt_x_kernel<<<2048, 256, 0, stream>>>(x, xh);
    build_frags_kernel<<<12, 256, 0, stream>>>(c1[0], c1[6], c2[0], c2[6], c3[0], c3[6], wfrag);
    partition_kernel<<<NPBLK, 256, 0, stream>>>(src, dst, gcount, pairbuf);
    bucket_scatter_kernel<<<NBUCK, 512, 0, stream>>>(pairbuf, gcount, cursor, csr);

    const int AGG_BLOCKS = 12500;  // 4 waves/block, 2 nodes/wave -> 100K nodes exactly
    const int MLP_BLOCKS = 1024;

    // ---- layer 1 (fin=13, 32 B rows): 16 edges/gather; MFMA MLP with K=32 (1 chunk) ----
    agg_vec_kernel<NFP, 4, 1><<<AGG_BLOCKS, 256, 0, stream>>>(xh, cursor, csr, yh);
    mlp_mfma_kernel<1><<<MLP_BLOCKS, 256, 0, stream>>>(
        yh, wfrag + 0 * 8192, c1[1], c1[2], c1[3], c1[4], c1[5], c1[7], h1);

    // ---- layer 2 (fin=64, 128 B rows): 8 edges/gather (16 B lanes); MFMA MLP K=64 ----
    agg_vec8_kernel<<<AGG_BLOCKS, 256, 0, stream>>>(h1, cursor, csr, yh);
    mlp_mfma_kernel<2><<<MLP_BLOCKS, 256, 0, stream>>>(
        yh, wfrag + 1 * 8192, c2[1], c2[2], c2[3], c2[4], c2[5], c2[7], h2);

    // ---- layer 3 (fin=64) ----
    agg_vec8_kernel<<<AGG_BLOCKS, 256, 0, stream>>>(h2, cursor, csr, yh);
    mlp_mfma_kernel<2><<<MLP_BLOCKS, 256, 0, stream>>>(
        yh, wfrag + 2 * 8192, c3[1], c3[2], c3[3], c3[4], c3[5], c3[7], h3);

    // ---- pooling (one wave per layer-chunk) + FC head ----
    pool_kernel<<<(NPTASK + 3) / 4, 256, 0, stream>>>(h1, h2, h3, batch, pool);
    head_kernel<<<NG, 192, 0, stream>>>(pool, fc1W, fc1b, fc2W, fc2b, out);
}